// Round 7
// baseline (455.293 us; speedup 1.0000x reference)
//
#include <hip/hip_runtime.h>
#include <hip/hip_fp16.h>

// AxialAttention: N=2, C=128, H=W=128, G=8, gp=16 (v), 8 (q/k)
// Pipeline:
//  k_transpose : x[b][c][h][w] -> xT[b][c][w][h]
//  k_wT        : weights -> WT[c][och] (och: 0-63 q, 64-127 k, 128-255 v)
//  k_qkv       : GEMM -> qkvT[(b*256+och)][w*128+i]  (BK=64, 32KB LDS)
//  k_qkv_stats : per-channel sum/sumsq of raw q,k,v (BN over N,H,W)
//  k_rel_tables: Rq/Pq/Rk/Pk tables for analytic qr/kr statistics
//  k_qkr_stats : per-(b,g,w) Gram matrices -> global stats of qk/qr/kr
//  k_relT      : q_rel/k_rel -> [d][c] transposed tables (overwrites tabs region, dead by then)
//  k_attn      : fused normalize + qk+qr+kr + softmax (branchless, 1/256-scaled) + sv/sve
//                LDS-minimized: f16 v_rel table (b64 reads, 2-way-free banks), hfma2 sve accum
//  k_sv_stats  : per-channel stats of sv/sve
//  k_final     : out = bn(sv)+bn(sve), transposed back to [b][c][h][w]

#define HW 16384   // H*W

__device__ __forceinline__ float warp_sum(float v) {
#pragma unroll
  for (int o = 32; o > 0; o >>= 1) v += __shfl_down(v, o);
  return v;
}

// ---------------- x transpose: per 128x128 plane ----------------
__global__ __launch_bounds__(256) void k_transpose(const float* __restrict__ in, float* __restrict__ out) {
  __shared__ float t[32][33];
  int plane = blockIdx.y;
  int th = (blockIdx.x >> 2) * 32;
  int tw = (blockIdx.x & 3) * 32;
  const float* p = in + (size_t)plane * HW;
  float* q = out + (size_t)plane * HW;
  int lx = threadIdx.x, ly = threadIdx.y;
#pragma unroll
  for (int r = ly; r < 32; r += 8) t[r][lx] = p[(th + r) * 128 + tw + lx];
  __syncthreads();
#pragma unroll
  for (int r = ly; r < 32; r += 8) q[(tw + r) * 128 + th + lx] = t[lx][r];
}

// ---------------- weight transpose: WT[c][och] 128x256 ----------------
__global__ __launch_bounds__(256) void k_wT(const float* __restrict__ wq, const float* __restrict__ wk,
                                            const float* __restrict__ wv, float* __restrict__ WT) {
  int idx = blockIdx.x * 256 + threadIdx.x;  // 32768 total
  int och = idx & 255, c = idx >> 8;
  const float* wrow = och < 64 ? wq + och * 128 : (och < 128 ? wk + (och - 64) * 128 : wv + (och - 128) * 128);
  WT[c * 256 + och] = wrow[c];
}

// ---------------- QKV GEMM (BK=64 -> 32KB LDS -> 5 blocks/CU) ----------------
__global__ __launch_bounds__(256) void k_qkv(const float* __restrict__ xT, const float* __restrict__ WT,
                                             float* __restrict__ qkvT) {
  __shared__ float Xs[64][64];  // [k][pix]
  __shared__ float Ws[64][64];  // [k][och]
  int pb = blockIdx.x * 64;
  int ob = blockIdx.y * 64;
  int b = blockIdx.z;
  const float* xb = xT + (size_t)b * (128 * HW);
  int tid = threadIdx.x;
  int tx = tid & 15, ty = tid >> 4;
  float acc[4][4] = {};
  for (int ks = 0; ks < 2; ++ks) {
    for (int idx = tid; idx < 4096; idx += 256) {
      int c = idx >> 6, p = idx & 63;
      Xs[c][p] = xb[(ks * 64 + c) * HW + pb + p];
    }
    for (int idx = tid; idx < 4096; idx += 256) {
      int c = idx >> 6, o = idx & 63;
      Ws[c][o] = WT[(ks * 64 + c) * 256 + ob + o];
    }
    __syncthreads();
#pragma unroll 8
    for (int kk = 0; kk < 64; ++kk) {
      float a0 = Ws[kk][ty * 4 + 0], a1 = Ws[kk][ty * 4 + 1], a2 = Ws[kk][ty * 4 + 2], a3 = Ws[kk][ty * 4 + 3];
      float4 bv = *reinterpret_cast<const float4*>(&Xs[kk][tx * 4]);
      acc[0][0] += a0 * bv.x; acc[0][1] += a0 * bv.y; acc[0][2] += a0 * bv.z; acc[0][3] += a0 * bv.w;
      acc[1][0] += a1 * bv.x; acc[1][1] += a1 * bv.y; acc[1][2] += a1 * bv.z; acc[1][3] += a1 * bv.w;
      acc[2][0] += a2 * bv.x; acc[2][1] += a2 * bv.y; acc[2][2] += a2 * bv.z; acc[2][3] += a2 * bv.w;
      acc[3][0] += a3 * bv.x; acc[3][1] += a3 * bv.y; acc[3][2] += a3 * bv.z; acc[3][3] += a3 * bv.w;
    }
    __syncthreads();
  }
#pragma unroll
  for (int r = 0; r < 4; ++r) {
    int row = ob + ty * 4 + r;
    float4 o4 = make_float4(acc[r][0], acc[r][1], acc[r][2], acc[r][3]);
    *reinterpret_cast<float4*>(&qkvT[(size_t)(b * 256 + row) * HW + pb + tx * 4]) = o4;
  }
}

// ---------------- per-channel stats of raw q/k/v ----------------
__global__ __launch_bounds__(256) void k_qkv_stats(const float* __restrict__ qkvT, double* __restrict__ statsQKV) {
  __shared__ float r1[4], r2[4];
  int ch = blockIdx.x;  // 0..255
  float s = 0.f, s2 = 0.f;
  for (int b = 0; b < 2; ++b) {
    const float* p = qkvT + (size_t)(b * 256 + ch) * HW;
    for (int idx = threadIdx.x; idx < HW; idx += 256) { float v = p[idx]; s += v; s2 += v * v; }
  }
  s = warp_sum(s); s2 = warp_sum(s2);
  int wid = threadIdx.x >> 6;
  if ((threadIdx.x & 63) == 0) { r1[wid] = s; r2[wid] = s2; }
  __syncthreads();
  if (threadIdx.x == 0) {
    statsQKV[2 * ch]     = (double)(r1[0] + r1[1] + r1[2] + r1[3]);
    statsQKV[2 * ch + 1] = (double)(r2[0] + r2[1] + r2[2] + r2[3]);
  }
}

// ---------------- rel tables for analytic stats ----------------
__global__ __launch_bounds__(128) void k_rel_tables(const float* __restrict__ q_rel, const float* __restrict__ k_rel,
                                                    float* __restrict__ tabs) {
  int tbl = blockIdx.x / 44, item = blockIdx.x % 44;
  const float* rel = tbl ? k_rel : q_rel;
  float* out = tabs + tbl * 5632;
  int i = threadIdx.x;  // 0..127
  float s = 0.f;
  if (item < 8) {
    const float* r = rel + item * 255 + i;
    for (int d = 0; d < 128; ++d) s += r[d];
  } else {
    int p = item - 8;
    int pp = p, c = 0;
    while (pp >= 8 - c) { pp -= 8 - c; ++c; }
    int c2 = c + pp;
    const float* ra = rel + c * 255 + i;
    const float* rb = rel + c2 * 255 + i;
    for (int d = 0; d < 128; ++d) s += ra[d] * rb[d];
  }
  out[item * 128 + i] = s;
}

// ---------------- analytic stats of qk/qr/kr via per-slice Gram matrices ----------------
__global__ __launch_bounds__(128) void k_qkr_stats(
    const float* __restrict__ qkvT, const double* __restrict__ statsQKV,
    const float* __restrict__ bnq_g, const float* __restrict__ bnq_b,
    const float* __restrict__ bnk_g, const float* __restrict__ bnk_b,
    const float* __restrict__ tabs, double* __restrict__ statsA) {
  __shared__ float red[92][2];
  int slice = blockIdx.x;  // (b*8+g)*128 + w
  int w = slice & 127, g = (slice >> 7) & 7, b = slice >> 10;
  int i = threadIdx.x;  // 0..127
  float qn[8], kn[8];
  const float* qbase = qkvT + (size_t)(b * 256 + g * 8) * HW + w * 128 + i;
  const float* kbase = qkvT + (size_t)(b * 256 + 64 + g * 8) * HW + w * 128 + i;
#pragma unroll
  for (int c = 0; c < 8; ++c) {
    {
      int och = g * 8 + c;
      double su = statsQKV[2 * och], sq = statsQKV[2 * och + 1];
      double mu = su * (1.0 / 32768.0);
      float var = (float)(sq * (1.0 / 32768.0) - mu * mu);
      float sc = bnq_g[och] * rsqrtf(var + 1e-5f);
      qn[c] = qbase[c * HW] * sc + (bnq_b[och] - (float)mu * sc);
    }
    {
      int gi = g * 8 + c, och = 64 + gi;
      double su = statsQKV[2 * och], sq = statsQKV[2 * och + 1];
      double mu = su * (1.0 / 32768.0);
      float var = (float)(sq * (1.0 / 32768.0) - mu * mu);
      float sc = bnk_g[gi] * rsqrtf(var + 1e-5f);
      kn[c] = kbase[c * HW] * sc + (bnk_b[gi] - (float)mu * sc);
    }
  }
  float vals[92];
  int n = 0;
#pragma unroll
  for (int c = 0; c < 8; ++c) vals[n++] = qn[c];
#pragma unroll
  for (int c = 0; c < 8; ++c) vals[n++] = kn[c];
#pragma unroll
  for (int c = 0; c < 8; ++c)
#pragma unroll
    for (int c2 = c; c2 < 8; ++c2) vals[n++] = qn[c] * qn[c2];
#pragma unroll
  for (int c = 0; c < 8; ++c)
#pragma unroll
    for (int c2 = c; c2 < 8; ++c2) vals[n++] = kn[c] * kn[c2];
  float sqr = 0.f, s2qr = 0.f, skr = 0.f, s2kr = 0.f;
#pragma unroll
  for (int c = 0; c < 8; ++c) {
    sqr += qn[c] * tabs[c * 128 + i];
    skr += kn[c] * tabs[5632 + c * 128 + i];
  }
  {
    int p = 0;
#pragma unroll
    for (int c = 0; c < 8; ++c)
#pragma unroll
      for (int c2 = c; c2 < 8; ++c2) {
        float f = (c == c2) ? 1.f : 2.f;
        s2qr += f * qn[c] * qn[c2] * tabs[1024 + p * 128 + i];
        s2kr += f * kn[c] * kn[c2] * tabs[5632 + 1024 + p * 128 + i];
        ++p;
      }
  }
  vals[88] = sqr; vals[89] = s2qr; vals[90] = skr; vals[91] = s2kr;
  int lane = i & 63, wid = i >> 6;
#pragma unroll
  for (int vv = 0; vv < 92; ++vv) {
    float r = warp_sum(vals[vv]);
    if (lane == 0) red[vv][wid] = r;
  }
  __syncthreads();
  if (i == 0) {
    float f[92];
#pragma unroll
    for (int vv = 0; vv < 92; ++vv) f[vv] = red[vv][0] + red[vv][1];
    float sS = 0.f, s2S = 0.f;
#pragma unroll
    for (int c = 0; c < 8; ++c) sS += f[c] * f[8 + c];
    {
      int p = 0;
#pragma unroll
      for (int c = 0; c < 8; ++c)
#pragma unroll
        for (int c2 = c; c2 < 8; ++c2) { float fm = (c == c2) ? 1.f : 2.f; s2S += fm * f[16 + p] * f[52 + p]; ++p; }
    }
    atomicAdd(&statsA[(0 * 8 + g) * 2 + 0], (double)sS);
    atomicAdd(&statsA[(0 * 8 + g) * 2 + 1], (double)s2S);
    atomicAdd(&statsA[(1 * 8 + g) * 2 + 0], (double)f[88]);
    atomicAdd(&statsA[(1 * 8 + g) * 2 + 1], (double)f[89]);
    atomicAdd(&statsA[(2 * 8 + g) * 2 + 0], (double)f[90]);
    atomicAdd(&statsA[(2 * 8 + g) * 2 + 1], (double)f[91]);
  }
}

// ---------------- q_rel/k_rel -> [d][c] transposed (runs after k_qkr_stats; reuses tabs) ----------------
__global__ __launch_bounds__(256) void k_relT(const float* __restrict__ q_rel, const float* __restrict__ k_rel,
                                              float* __restrict__ relT) {
  int idx = blockIdx.x * 256 + threadIdx.x;  // 4080 total
  if (idx < 2040) {
    int d = idx >> 3, c = idx & 7;
    relT[idx] = q_rel[c * 255 + d];
  } else if (idx < 4080) {
    int j = idx - 2040;
    int d = j >> 3, c = j & 7;
    relT[2040 + j] = k_rel[c * 255 + d];
  }
}

// ---------------- fused attention per slice ----------------
__global__ __launch_bounds__(256) void k_attn(
    const float* __restrict__ qkvT,
    const double* __restrict__ statsQKV, const double* __restrict__ statsA,
    const float* __restrict__ relTq, const float* __restrict__ relTk, const float* __restrict__ v_rel,
    const float* __restrict__ bnq_g, const float* __restrict__ bnq_b,
    const float* __restrict__ bnk_g, const float* __restrict__ bnk_b,
    const float* __restrict__ bnv_g, const float* __restrict__ bnv_b,
    const float* __restrict__ bnqk_g, const float* __restrict__ bnqk_b,
    const float* __restrict__ bnqr_g, const float* __restrict__ bnqr_b,
    const float* __restrict__ bnkr_g, const float* __restrict__ bnkr_b,
    float* __restrict__ svT, float* __restrict__ sveT) {
  __shared__ float Ks[128][8];     // [j][c] normalized K (broadcast b128 reads)
  __shared__ float Vs[128][16];    // [j][c] normalized V (broadcast b128 reads)
  __shared__ __half Wr[255 * 20];  // [d][c] v_rel f16; 20-half rows: b64-aligned all rows, 2-way banks (free)
  __shared__ float nsc[32], nsh[32];
  int slice = blockIdx.x;
  int w = slice & 127, g = (slice >> 7) & 7, b = slice >> 10;
  int tid = threadIdx.x;
  if (tid < 32) {
    int och, gi; const float* gm; const float* bt;
    if (tid < 8)       { gi = g * 8 + tid;        och = gi;       gm = bnq_g; bt = bnq_b; }
    else if (tid < 16) { gi = g * 8 + (tid - 8);  och = 64 + gi;  gm = bnk_g; bt = bnk_b; }
    else               { gi = g * 16 + (tid - 16); och = 128 + gi; gm = bnv_g; bt = bnv_b; }
    double su = statsQKV[2 * och], sq = statsQKV[2 * och + 1];
    double mu = su * (1.0 / 32768.0);
    float var = (float)(sq * (1.0 / 32768.0) - mu * mu);
    float sc = gm[gi] * rsqrtf(var + 1e-5f);
    nsc[tid] = sc;
    nsh[tid] = bt[gi] - (float)mu * sc;
  }
  __syncthreads();
  {
    const float* kbase = qkvT + (size_t)(b * 256 + 64 + g * 8) * HW + w * 128;
    for (int idx = tid; idx < 1024; idx += 256) {
      int c = idx >> 7, jj = idx & 127;
      Ks[jj][c] = kbase[c * HW + jj] * nsc[8 + c] + nsh[8 + c];
    }
    const float* vbase = qkvT + (size_t)(b * 256 + 128 + g * 16) * HW + w * 128;
    for (int idx = tid; idx < 2048; idx += 256) {
      int c = idx >> 7, jj = idx & 127;
      Vs[jj][c] = vbase[c * HW + jj] * nsc[16 + c] + nsh[16 + c];
    }
    for (int idx = tid; idx < 4096; idx += 256) {
      int c = idx >> 8, d = idx & 255;
      if (d < 255) Wr[d * 20 + c] = __float2half(v_rel[c * 255 + d]);
    }
  }
  int i = tid >> 1, h = tid & 1;
  float qreg[8];
  {
    const float* qbase = qkvT + (size_t)(b * 256 + g * 8) * HW + w * 128;
#pragma unroll
    for (int c = 0; c < 8; ++c) qreg[c] = qbase[c * HW + i] * nsc[c] + nsh[c];
  }
  float aS, aQR, aKR, offs;
  {
    const double inv = 1.0 / 4194304.0;  // N*H*H*W per group
    double s0 = statsA[(0 * 8 + g) * 2], q0 = statsA[(0 * 8 + g) * 2 + 1];
    double s1 = statsA[(1 * 8 + g) * 2], q1 = statsA[(1 * 8 + g) * 2 + 1];
    double s2 = statsA[(2 * 8 + g) * 2], q2 = statsA[(2 * 8 + g) * 2 + 1];
    double m0 = s0 * inv, m1 = s1 * inv, m2 = s2 * inv;
    float v0 = (float)(q0 * inv - m0 * m0);
    float v1 = (float)(q1 * inv - m1 * m1);
    float v2 = (float)(q2 * inv - m2 * m2);
    aS  = bnqk_g[g] * rsqrtf(v0 + 1e-5f);
    aQR = bnqr_g[g] * rsqrtf(v1 + 1e-5f);
    aKR = bnkr_g[g] * rsqrtf(v2 + 1e-5f);
    offs = (bnqk_b[g] - (float)m0 * aS) + (bnqr_b[g] - (float)m1 * aQR) + (bnkr_b[g] - (float)m2 * aKR);
    offs -= 5.545177444479562f;  // *1/256 on all exp(): softmax-invariant, guards f16 accum overflow
  }
  __syncthreads();

  const int jbase = h << 6;
  float l = 0.f;
  float asv[16] = {};
  __half2 hacc[8];
#pragma unroll
  for (int u = 0; u < 8; ++u) hacc[u] = __float2half2_rn(0.f);
  const float* qrp = relTq + (size_t)(127 + i - jbase) * 8;  // -8 per jj
  const float* krp = relTk + (size_t)(127 - i + jbase) * 8;  // +8 per jj
  const __half* wp = Wr + (127 - i + jbase) * 20;            // +20 per jj
  const float* kp  = &Ks[jbase][0];                          // +8 per jj
  const float* vp  = &Vs[jbase][0];                          // +16 per jj

#pragma unroll 2
  for (int jj = 0; jj < 64; ++jj) {
    float4 ka = *reinterpret_cast<const float4*>(kp);
    float4 kb = *reinterpret_cast<const float4*>(kp + 4);
    float4 qa = *reinterpret_cast<const float4*>(qrp);
    float4 qb = *reinterpret_cast<const float4*>(qrp + 4);
    float4 ra = *reinterpret_cast<const float4*>(krp);
    float4 rb = *reinterpret_cast<const float4*>(krp + 4);
    float S  = qreg[0] * ka.x + qreg[1] * ka.y + qreg[2] * ka.z + qreg[3] * ka.w
             + qreg[4] * kb.x + qreg[5] * kb.y + qreg[6] * kb.z + qreg[7] * kb.w;
    float QR = qreg[0] * qa.x + qreg[1] * qa.y + qreg[2] * qa.z + qreg[3] * qa.w
             + qreg[4] * qb.x + qreg[5] * qb.y + qreg[6] * qb.z + qreg[7] * qb.w;
    float KR = ka.x * ra.x + ka.y * ra.y + ka.z * ra.z + ka.w * ra.w
             + kb.x * rb.x + kb.y * rb.y + kb.z * rb.z + kb.w * rb.w;
    float a = fmaf(S, aS, fmaf(QR, aQR, fmaf(KR, aKR, offs)));
    float e = __expf(a);   // BN-normalized scores (pre-scaled by 1/256): no max tracking needed
    l += e;
    float4 v0 = *reinterpret_cast<const float4*>(vp);
    float4 v1 = *reinterpret_cast<const float4*>(vp + 4);
    float4 v2 = *reinterpret_cast<const float4*>(vp + 8);
    float4 v3 = *reinterpret_cast<const float4*>(vp + 12);
    asv[0]  += e * v0.x; asv[1]  += e * v0.y; asv[2]  += e * v0.z; asv[3]  += e * v0.w;
    asv[4]  += e * v1.x; asv[5]  += e * v1.y; asv[6]  += e * v1.z; asv[7]  += e * v1.w;
    asv[8]  += e * v2.x; asv[9]  += e * v2.y; asv[10] += e * v2.z; asv[11] += e * v2.w;
    asv[12] += e * v3.x; asv[13] += e * v3.y; asv[14] += e * v3.z; asv[15] += e * v3.w;
    // sve: f16 packed accumulate from the f16 diag table (4x ds_read_b64, 2-way-free)
    __half2 eh2 = __float2half2_rn(e);
    float2 w0 = *reinterpret_cast<const float2*>(wp);
    float2 w1 = *reinterpret_cast<const float2*>(wp + 4);
    float2 w2 = *reinterpret_cast<const float2*>(wp + 8);
    float2 w3 = *reinterpret_cast<const float2*>(wp + 12);
    const __half2* h0 = reinterpret_cast<const __half2*>(&w0);
    const __half2* h1 = reinterpret_cast<const __half2*>(&w1);
    const __half2* h2 = reinterpret_cast<const __half2*>(&w2);
    const __half2* h3 = reinterpret_cast<const __half2*>(&w3);
    hacc[0] = __hfma2(eh2, h0[0], hacc[0]); hacc[1] = __hfma2(eh2, h0[1], hacc[1]);
    hacc[2] = __hfma2(eh2, h1[0], hacc[2]); hacc[3] = __hfma2(eh2, h1[1], hacc[3]);
    hacc[4] = __hfma2(eh2, h2[0], hacc[4]); hacc[5] = __hfma2(eh2, h2[1], hacc[5]);
    hacc[6] = __hfma2(eh2, h3[0], hacc[6]); hacc[7] = __hfma2(eh2, h3[1], hacc[7]);
    qrp -= 8; krp += 8; wp += 20; kp += 8; vp += 16;
  }
  // combine the two j-halves (partner lane tid^1)
  float L = l + __shfl_xor(l, 1);
  float linv = 1.f / L;
  float* outp = (h ? sveT : svT) + (size_t)slice * 2048 + i;
#pragma unroll
  for (int c = 0; c < 16; ++c) {
    float vsv = asv[c] + __shfl_xor(asv[c], 1);
    float hv = (c & 1) ? __high2float(hacc[c >> 1]) : __low2float(hacc[c >> 1]);
    float vse = hv + __shfl_xor(hv, 1);
    outp[c * 128] = (h ? vse : vsv) * linv;
  }
}

// ---------------- per-channel stats of sv/sve ----------------
__global__ __launch_bounds__(256) void k_sv_stats(const float* __restrict__ svT, const float* __restrict__ sveT,
                                                  double* __restrict__ statsSV) {
  __shared__ float r1[4], r2[4];
  int ch = blockIdx.x;  // 0-127 sv, 128-255 sve
  const float* base = (ch < 128) ? svT : sveT;
  int c = ch & 127, g = c >> 4, cc = c & 15;
  float s = 0.f, s2 = 0.f;
  for (int idx = threadIdx.x; idx < 32768; idx += 256) {
    int bw = idx >> 7, ii = idx & 127;
    int bb = bw >> 7, wwi = bw & 127;
    float v = base[(size_t)(((bb * 8 + g) * 128) + wwi) * 2048 + cc * 128 + ii];
    s += v; s2 += v * v;
  }
  s = warp_sum(s); s2 = warp_sum(s2);
  int wid = threadIdx.x >> 6;
  if ((threadIdx.x & 63) == 0) { r1[wid] = s; r2[wid] = s2; }
  __syncthreads();
  if (threadIdx.x == 0) {
    statsSV[2 * ch]     = (double)(r1[0] + r1[1] + r1[2] + r1[3]);
    statsSV[2 * ch + 1] = (double)(r2[0] + r2[1] + r2[2] + r2[3]);
  }
}

// ---------------- final: out = bn(sv)+bn(sve), transpose (w,i)->(i,w) ----------------
__global__ __launch_bounds__(256) void k_final(const float* __restrict__ svT, const float* __restrict__ sveT,
                                               const double* __restrict__ statsSV,
                                               const float* __restrict__ bnsv_g, const float* __restrict__ bnsv_b,
                                               const float* __restrict__ bnsve_g, const float* __restrict__ bnsve_b,
                                               float* __restrict__ out) {
  __shared__ float t[32][33];
  int plane = blockIdx.y;  // b*128 + c
  int b = plane >> 7, c = plane & 127;
  int g = c >> 4, cc = c & 15;
  double s = statsSV[2 * c], s2 = statsSV[2 * c + 1];
  double mu1 = s * (1.0 / 32768.0);
  float var1 = (float)(s2 * (1.0 / 32768.0) - mu1 * mu1);
  float sc1 = bnsv_g[c] * rsqrtf(var1 + 1e-5f);
  float sh1 = bnsv_b[c] - (float)mu1 * sc1;
  double se = statsSV[2 * (128 + c)], se2 = statsSV[2 * (128 + c) + 1];
  double mu2 = se * (1.0 / 32768.0);
  float var2 = (float)(se2 * (1.0 / 32768.0) - mu2 * mu2);
  float sc2 = bnsve_g[c] * rsqrtf(var2 + 1e-5f);
  float sh2 = bnsve_b[c] - (float)mu2 * sc2;
  int tw = (blockIdx.x & 3) * 32, ti = (blockIdx.x >> 2) * 32;
  int lx = threadIdx.x, ly = threadIdx.y;
#pragma unroll
  for (int r = ly; r < 32; r += 8) {
    int wr = tw + r, ii = ti + lx;
    size_t off = (size_t)((b * 8 + g) * 128 + wr) * 2048 + cc * 128 + ii;
    t[r][lx] = svT[off] * sc1 + sh1 + sveT[off] * sc2 + sh2;
  }
  __syncthreads();
#pragma unroll
  for (int r = ly; r < 32; r += 8)
    out[(size_t)plane * HW + (ti + r) * 128 + tw + lx] = t[lx][r];
}

extern "C" void kernel_launch(void* const* d_in, const int* in_sizes, int n_in,
                              void* d_out, int out_size, void* d_ws, size_t ws_size,
                              hipStream_t stream) {
  const float* x      = (const float*)d_in[0];
  const float* wq     = (const float*)d_in[1];
  const float* wk     = (const float*)d_in[2];
  const float* wv     = (const float*)d_in[3];
  const float* q_rel  = (const float*)d_in[4];
  const float* k_rel  = (const float*)d_in[5];
  const float* v_rel  = (const float*)d_in[6];
  const float* bnq_g  = (const float*)d_in[7];
  const float* bnq_b  = (const float*)d_in[8];
  const float* bnk_g  = (const float*)d_in[9];
  const float* bnk_b  = (const float*)d_in[10];
  const float* bnv_g  = (const float*)d_in[11];
  const float* bnv_b  = (const float*)d_in[12];
  const float* bnqk_g = (const float*)d_in[13];
  const float* bnqk_b = (const float*)d_in[14];
  const float* bnqr_g = (const float*)d_in[15];
  const float* bnqr_b = (const float*)d_in[16];
  const float* bnkr_g = (const float*)d_in[17];
  const float* bnkr_b = (const float*)d_in[18];
  const float* bnsv_g = (const float*)d_in[19];
  const float* bnsv_b = (const float*)d_in[20];
  const float* bnsve_g = (const float*)d_in[21];
  const float* bnsve_b = (const float*)d_in[22];
  float* out = (float*)d_out;

  float* wsf  = (float*)d_ws;
  float* xT   = wsf;              // 4,194,304 floats (reused as svT later: lifetimes disjoint)
  float* svT  = wsf;
  float* qkvT = wsf + 4194304;    // 8,388,608 floats
  float* sveT = wsf + 12582912;   // 4,194,304 floats
  float* tabs = wsf + 16777216;   // 11,264 floats; after k_qkr_stats reused as relT (4,080 floats)
  float* relTq = tabs;
  float* relTk = tabs + 2040;
  float* WT   = wsf + 16788480;   // 32,768 floats
  double* statsQKV = (double*)(wsf + 16821248);  // 512 doubles
  double* statsA   = statsQKV + 512;             // 48 doubles
  double* statsSV  = statsA + 48;                // 512 doubles

  hipMemsetAsync(statsA, 0, 48 * sizeof(double), stream);
  k_transpose<<<dim3(16, 256), dim3(32, 8), 0, stream>>>(x, xT);
  k_wT<<<128, 256, 0, stream>>>(wq, wk, wv, WT);
  k_qkv<<<dim3(256, 4, 2), 256, 0, stream>>>(xT, WT, qkvT);
  k_qkv_stats<<<256, 256, 0, stream>>>(qkvT, statsQKV);
  k_rel_tables<<<88, 128, 0, stream>>>(q_rel, k_rel, tabs);
  k_qkr_stats<<<2048, 128, 0, stream>>>(qkvT, statsQKV, bnq_g, bnq_b, bnk_g, bnk_b, tabs, statsA);
  k_relT<<<16, 256, 0, stream>>>(q_rel, k_rel, relTq);  // overwrites tabs (dead after k_qkr_stats)
  k_attn<<<2048, 256, 0, stream>>>(qkvT, statsQKV, statsA, relTq, relTk, v_rel,
                                   bnq_g, bnq_b, bnk_g, bnk_b, bnv_g, bnv_b,
                                   bnqk_g, bnqk_b, bnqr_g, bnqr_b, bnkr_g, bnkr_b,
                                   svT, sveT);
  k_sv_stats<<<256, 256, 0, stream>>>(svT, sveT, statsSV);
  k_final<<<dim3(16, 256), dim3(32, 8), 0, stream>>>(svT, sveT, statsSV,
                                                     bnsv_g, bnsv_b, bnsve_g, bnsve_b, out);
  (void)in_sizes; (void)n_in; (void)out_size; (void)ws_size;
}

// Round 8
// 414.211 us; speedup vs baseline: 1.0992x; 1.0992x over previous
//
#include <hip/hip_runtime.h>
#include <hip/hip_fp16.h>

// AxialAttention: N=2, C=128, H=W=128, G=8, gp=16 (v), 8 (q/k)
// k_attn v3: 2 rows/thread, slice-per-wave (4 slices/block), conflict-free
// chunked f16 v_rel gather (Wh[2][255][8], 16B rows), qr/kr via L1 global.

#define HW 16384   // H*W

__device__ __forceinline__ float warp_sum(float v) {
#pragma unroll
  for (int o = 32; o > 0; o >>= 1) v += __shfl_down(v, o);
  return v;
}

// ---------------- x transpose: per 128x128 plane ----------------
__global__ __launch_bounds__(256) void k_transpose(const float* __restrict__ in, float* __restrict__ out) {
  __shared__ float t[32][33];
  int plane = blockIdx.y;
  int th = (blockIdx.x >> 2) * 32;
  int tw = (blockIdx.x & 3) * 32;
  const float* p = in + (size_t)plane * HW;
  float* q = out + (size_t)plane * HW;
  int lx = threadIdx.x, ly = threadIdx.y;
#pragma unroll
  for (int r = ly; r < 32; r += 8) t[r][lx] = p[(th + r) * 128 + tw + lx];
  __syncthreads();
#pragma unroll
  for (int r = ly; r < 32; r += 8) q[(tw + r) * 128 + th + lx] = t[lx][r];
}

// ---------------- weight transpose: WT[c][och] 128x256 ----------------
__global__ __launch_bounds__(256) void k_wT(const float* __restrict__ wq, const float* __restrict__ wk,
                                            const float* __restrict__ wv, float* __restrict__ WT) {
  int idx = blockIdx.x * 256 + threadIdx.x;  // 32768 total
  int och = idx & 255, c = idx >> 8;
  const float* wrow = och < 64 ? wq + och * 128 : (och < 128 ? wk + (och - 64) * 128 : wv + (och - 128) * 128);
  WT[c * 256 + och] = wrow[c];
}

// ---------------- QKV GEMM (BK=64 -> 32KB LDS -> 5 blocks/CU) ----------------
__global__ __launch_bounds__(256) void k_qkv(const float* __restrict__ xT, const float* __restrict__ WT,
                                             float* __restrict__ qkvT) {
  __shared__ float Xs[64][64];  // [k][pix]
  __shared__ float Ws[64][64];  // [k][och]
  int pb = blockIdx.x * 64;
  int ob = blockIdx.y * 64;
  int b = blockIdx.z;
  const float* xb = xT + (size_t)b * (128 * HW);
  int tid = threadIdx.x;
  int tx = tid & 15, ty = tid >> 4;
  float acc[4][4] = {};
  for (int ks = 0; ks < 2; ++ks) {
    for (int idx = tid; idx < 4096; idx += 256) {
      int c = idx >> 6, p = idx & 63;
      Xs[c][p] = xb[(ks * 64 + c) * HW + pb + p];
    }
    for (int idx = tid; idx < 4096; idx += 256) {
      int c = idx >> 6, o = idx & 63;
      Ws[c][o] = WT[(ks * 64 + c) * 256 + ob + o];
    }
    __syncthreads();
#pragma unroll 8
    for (int kk = 0; kk < 64; ++kk) {
      float a0 = Ws[kk][ty * 4 + 0], a1 = Ws[kk][ty * 4 + 1], a2 = Ws[kk][ty * 4 + 2], a3 = Ws[kk][ty * 4 + 3];
      float4 bv = *reinterpret_cast<const float4*>(&Xs[kk][tx * 4]);
      acc[0][0] += a0 * bv.x; acc[0][1] += a0 * bv.y; acc[0][2] += a0 * bv.z; acc[0][3] += a0 * bv.w;
      acc[1][0] += a1 * bv.x; acc[1][1] += a1 * bv.y; acc[1][2] += a1 * bv.z; acc[1][3] += a1 * bv.w;
      acc[2][0] += a2 * bv.x; acc[2][1] += a2 * bv.y; acc[2][2] += a2 * bv.z; acc[2][3] += a2 * bv.w;
      acc[3][0] += a3 * bv.x; acc[3][1] += a3 * bv.y; acc[3][2] += a3 * bv.z; acc[3][3] += a3 * bv.w;
    }
    __syncthreads();
  }
#pragma unroll
  for (int r = 0; r < 4; ++r) {
    int row = ob + ty * 4 + r;
    float4 o4 = make_float4(acc[r][0], acc[r][1], acc[r][2], acc[r][3]);
    *reinterpret_cast<float4*>(&qkvT[(size_t)(b * 256 + row) * HW + pb + tx * 4]) = o4;
  }
}

// ---------------- per-channel stats of raw q/k/v ----------------
__global__ __launch_bounds__(256) void k_qkv_stats(const float* __restrict__ qkvT, double* __restrict__ statsQKV) {
  __shared__ float r1[4], r2[4];
  int ch = blockIdx.x;  // 0..255
  float s = 0.f, s2 = 0.f;
  for (int b = 0; b < 2; ++b) {
    const float* p = qkvT + (size_t)(b * 256 + ch) * HW;
    for (int idx = threadIdx.x; idx < HW; idx += 256) { float v = p[idx]; s += v; s2 += v * v; }
  }
  s = warp_sum(s); s2 = warp_sum(s2);
  int wid = threadIdx.x >> 6;
  if ((threadIdx.x & 63) == 0) { r1[wid] = s; r2[wid] = s2; }
  __syncthreads();
  if (threadIdx.x == 0) {
    statsQKV[2 * ch]     = (double)(r1[0] + r1[1] + r1[2] + r1[3]);
    statsQKV[2 * ch + 1] = (double)(r2[0] + r2[1] + r2[2] + r2[3]);
  }
}

// ---------------- rel tables for analytic stats ----------------
__global__ __launch_bounds__(128) void k_rel_tables(const float* __restrict__ q_rel, const float* __restrict__ k_rel,
                                                    float* __restrict__ tabs) {
  int tbl = blockIdx.x / 44, item = blockIdx.x % 44;
  const float* rel = tbl ? k_rel : q_rel;
  float* out = tabs + tbl * 5632;
  int i = threadIdx.x;  // 0..127
  float s = 0.f;
  if (item < 8) {
    const float* r = rel + item * 255 + i;
    for (int d = 0; d < 128; ++d) s += r[d];
  } else {
    int p = item - 8;
    int pp = p, c = 0;
    while (pp >= 8 - c) { pp -= 8 - c; ++c; }
    int c2 = c + pp;
    const float* ra = rel + c * 255 + i;
    const float* rb = rel + c2 * 255 + i;
    for (int d = 0; d < 128; ++d) s += ra[d] * rb[d];
  }
  out[item * 128 + i] = s;
}

// ---------------- analytic stats of qk/qr/kr via per-slice Gram matrices ----------------
__global__ __launch_bounds__(128) void k_qkr_stats(
    const float* __restrict__ qkvT, const double* __restrict__ statsQKV,
    const float* __restrict__ bnq_g, const float* __restrict__ bnq_b,
    const float* __restrict__ bnk_g, const float* __restrict__ bnk_b,
    const float* __restrict__ tabs, double* __restrict__ statsA) {
  __shared__ float red[92][2];
  int slice = blockIdx.x;  // (b*8+g)*128 + w
  int w = slice & 127, g = (slice >> 7) & 7, b = slice >> 10;
  int i = threadIdx.x;  // 0..127
  float qn[8], kn[8];
  const float* qbase = qkvT + (size_t)(b * 256 + g * 8) * HW + w * 128 + i;
  const float* kbase = qkvT + (size_t)(b * 256 + 64 + g * 8) * HW + w * 128 + i;
#pragma unroll
  for (int c = 0; c < 8; ++c) {
    {
      int och = g * 8 + c;
      double su = statsQKV[2 * och], sq = statsQKV[2 * och + 1];
      double mu = su * (1.0 / 32768.0);
      float var = (float)(sq * (1.0 / 32768.0) - mu * mu);
      float sc = bnq_g[och] * rsqrtf(var + 1e-5f);
      qn[c] = qbase[c * HW] * sc + (bnq_b[och] - (float)mu * sc);
    }
    {
      int gi = g * 8 + c, och = 64 + gi;
      double su = statsQKV[2 * och], sq = statsQKV[2 * och + 1];
      double mu = su * (1.0 / 32768.0);
      float var = (float)(sq * (1.0 / 32768.0) - mu * mu);
      float sc = bnk_g[gi] * rsqrtf(var + 1e-5f);
      kn[c] = kbase[c * HW] * sc + (bnk_b[gi] - (float)mu * sc);
    }
  }
  float vals[92];
  int n = 0;
#pragma unroll
  for (int c = 0; c < 8; ++c) vals[n++] = qn[c];
#pragma unroll
  for (int c = 0; c < 8; ++c) vals[n++] = kn[c];
#pragma unroll
  for (int c = 0; c < 8; ++c)
#pragma unroll
    for (int c2 = c; c2 < 8; ++c2) vals[n++] = qn[c] * qn[c2];
#pragma unroll
  for (int c = 0; c < 8; ++c)
#pragma unroll
    for (int c2 = c; c2 < 8; ++c2) vals[n++] = kn[c] * kn[c2];
  float sqr = 0.f, s2qr = 0.f, skr = 0.f, s2kr = 0.f;
#pragma unroll
  for (int c = 0; c < 8; ++c) {
    sqr += qn[c] * tabs[c * 128 + i];
    skr += kn[c] * tabs[5632 + c * 128 + i];
  }
  {
    int p = 0;
#pragma unroll
    for (int c = 0; c < 8; ++c)
#pragma unroll
      for (int c2 = c; c2 < 8; ++c2) {
        float f = (c == c2) ? 1.f : 2.f;
        s2qr += f * qn[c] * qn[c2] * tabs[1024 + p * 128 + i];
        s2kr += f * kn[c] * kn[c2] * tabs[5632 + 1024 + p * 128 + i];
        ++p;
      }
  }
  vals[88] = sqr; vals[89] = s2qr; vals[90] = skr; vals[91] = s2kr;
  int lane = i & 63, wid = i >> 6;
#pragma unroll
  for (int vv = 0; vv < 92; ++vv) {
    float r = warp_sum(vals[vv]);
    if (lane == 0) red[vv][wid] = r;
  }
  __syncthreads();
  if (i == 0) {
    float f[92];
#pragma unroll
    for (int vv = 0; vv < 92; ++vv) f[vv] = red[vv][0] + red[vv][1];
    float sS = 0.f, s2S = 0.f;
#pragma unroll
    for (int c = 0; c < 8; ++c) sS += f[c] * f[8 + c];
    {
      int p = 0;
#pragma unroll
      for (int c = 0; c < 8; ++c)
#pragma unroll
        for (int c2 = c; c2 < 8; ++c2) { float fm = (c == c2) ? 1.f : 2.f; s2S += fm * f[16 + p] * f[52 + p]; ++p; }
    }
    atomicAdd(&statsA[(0 * 8 + g) * 2 + 0], (double)sS);
    atomicAdd(&statsA[(0 * 8 + g) * 2 + 1], (double)s2S);
    atomicAdd(&statsA[(1 * 8 + g) * 2 + 0], (double)f[88]);
    atomicAdd(&statsA[(1 * 8 + g) * 2 + 1], (double)f[89]);
    atomicAdd(&statsA[(2 * 8 + g) * 2 + 0], (double)f[90]);
    atomicAdd(&statsA[(2 * 8 + g) * 2 + 1], (double)f[91]);
  }
}

// ---------------- q_rel/k_rel -> [d][c] transposed (runs after k_qkr_stats; reuses tabs) ----------------
__global__ __launch_bounds__(256) void k_relT(const float* __restrict__ q_rel, const float* __restrict__ k_rel,
                                              float* __restrict__ relT) {
  int idx = blockIdx.x * 256 + threadIdx.x;  // 4080 total
  if (idx < 2040) {
    int d = idx >> 3, c = idx & 7;
    relT[idx] = q_rel[c * 255 + d];
  } else if (idx < 4080) {
    int j = idx - 2040;
    int d = j >> 3, c = j & 7;
    relT[2040 + j] = k_rel[c * 255 + d];
  }
}

// ---------------- fused attention: 4 slices/block, slice per wave, 2 rows/thread ----------------
__global__ __launch_bounds__(256) void k_attn(
    const float* __restrict__ qkvT,
    const double* __restrict__ statsQKV, const double* __restrict__ statsA,
    const float* __restrict__ relTq, const float* __restrict__ relTk, const float* __restrict__ v_rel,
    const float* __restrict__ bnq_g, const float* __restrict__ bnq_b,
    const float* __restrict__ bnk_g, const float* __restrict__ bnk_b,
    const float* __restrict__ bnv_g, const float* __restrict__ bnv_b,
    const float* __restrict__ bnqk_g, const float* __restrict__ bnqk_b,
    const float* __restrict__ bnqr_g, const float* __restrict__ bnqr_b,
    const float* __restrict__ bnkr_g, const float* __restrict__ bnkr_b,
    float* __restrict__ svT, float* __restrict__ sveT) {
  __shared__ float Ks[4][128][8];    // [slice][j][c] normalized K (uniform-addr broadcast b128)
  __shared__ float Vs[4][128][16];   // [slice][j][c] normalized V
  __shared__ __half Wh[2][255][8];   // chunked f16 v_rel: Wh[c8][d][e] = v_rel[c8*8+e][d]; 16B rows -> conflict-free b128 gather
  __shared__ float nsc[32], nsh[32];
  int tid = threadIdx.x;
  int slice0 = blockIdx.x * 4;
  int w0 = slice0 & 127, g = (slice0 >> 7) & 7, b = slice0 >> 10;  // (b,g) uniform over the 4 slices
  if (tid < 32) {
    int och, gi; const float* gm; const float* bt;
    if (tid < 8)       { gi = g * 8 + tid;        och = gi;       gm = bnq_g; bt = bnq_b; }
    else if (tid < 16) { gi = g * 8 + (tid - 8);  och = 64 + gi;  gm = bnk_g; bt = bnk_b; }
    else               { gi = g * 16 + (tid - 16); och = 128 + gi; gm = bnv_g; bt = bnv_b; }
    double su = statsQKV[2 * och], sq = statsQKV[2 * och + 1];
    double mu = su * (1.0 / 32768.0);
    float var = (float)(sq * (1.0 / 32768.0) - mu * mu);
    float sc = gm[gi] * rsqrtf(var + 1e-5f);
    nsc[tid] = sc;
    nsh[tid] = bt[gi] - (float)mu * sc;
  }
  __syncthreads();
  // staging (global reads coalesced over j; LDS write conflicts once-per-block, negligible)
  for (int idx = tid; idx < 4096; idx += 256) {
    int j = idx & 127, c = (idx >> 7) & 7, s = idx >> 10;
    Ks[s][j][c] = qkvT[(size_t)(b * 256 + 64 + g * 8 + c) * HW + (w0 + s) * 128 + j] * nsc[8 + c] + nsh[8 + c];
  }
  for (int idx = tid; idx < 8192; idx += 256) {
    int j = idx & 127, c = (idx >> 7) & 15, s = idx >> 11;
    Vs[s][j][c] = qkvT[(size_t)(b * 256 + 128 + g * 16 + c) * HW + (w0 + s) * 128 + j] * nsc[16 + c] + nsh[16 + c];
  }
  for (int idx = tid; idx < 4080; idx += 256) {
    int c8 = idx / 2040, r = idx - c8 * 2040, d = r >> 3, e = r & 7;
    Wh[c8][d][e] = __float2half(v_rel[(c8 * 8 + e) * 255 + d]);
  }
  float aS, aQR, aKR, offs;
  {
    const double inv = 1.0 / 4194304.0;  // N*H*H*W per group
    double s0 = statsA[(0 * 8 + g) * 2], q0 = statsA[(0 * 8 + g) * 2 + 1];
    double s1 = statsA[(1 * 8 + g) * 2], q1 = statsA[(1 * 8 + g) * 2 + 1];
    double s2 = statsA[(2 * 8 + g) * 2], q2 = statsA[(2 * 8 + g) * 2 + 1];
    double m0 = s0 * inv, m1 = s1 * inv, m2 = s2 * inv;
    float v0 = (float)(q0 * inv - m0 * m0);
    float v1 = (float)(q1 * inv - m1 * m1);
    float v2 = (float)(q2 * inv - m2 * m2);
    aS  = bnqk_g[g] * rsqrtf(v0 + 1e-5f);
    aQR = bnqr_g[g] * rsqrtf(v1 + 1e-5f);
    aKR = bnkr_g[g] * rsqrtf(v2 + 1e-5f);
    offs = (bnqk_b[g] - (float)m0 * aS) + (bnqr_b[g] - (float)m1 * aQR) + (bnkr_b[g] - (float)m2 * aKR);
    offs -= 5.545177444479562f;  // *1/256 on all exp(): softmax-invariant, guards f16 accum overflow
  }
  __syncthreads();

  int wv = tid >> 6, lane = tid & 63;
  int slice = slice0 + wv, w = w0 + wv;
  int i0 = lane, i1 = lane + 64;
  float q0r[8], q1r[8];
  {
    const float* qbase = qkvT + (size_t)(b * 256 + g * 8) * HW + w * 128;
#pragma unroll
    for (int c = 0; c < 8; ++c) {
      q0r[c] = qbase[c * HW + i0] * nsc[c] + nsh[c];
      q1r[c] = qbase[c * HW + i1] * nsc[c] + nsh[c];
    }
  }
  float l0 = 0.f, l1 = 0.f;
  float asv0[16] = {}, asv1[16] = {};
  __half2 ha0[8], ha1[8];
#pragma unroll
  for (int u = 0; u < 8; ++u) { ha0[u] = __float2half2_rn(0.f); ha1[u] = __float2half2_rn(0.f); }
  const float* Kp = &Ks[wv][0][0];
  const float* Vp = &Vs[wv][0][0];

#pragma unroll 2
  for (int j = 0; j < 128; ++j) {
    float4 ka = *reinterpret_cast<const float4*>(Kp + j * 8);
    float4 kb = *reinterpret_cast<const float4*>(Kp + j * 8 + 4);
    int dq = 127 + i0 - j;   // qr row (i0); i1 row = dq+64
    int d0 = 127 - i0 + j;   // kr & v_rel row (i0); i1 row = d0-64
    const float4* qp0 = reinterpret_cast<const float4*>(relTq + dq * 8);
    const float4* qp1 = reinterpret_cast<const float4*>(relTq + (dq + 64) * 8);
    const float4* rp0 = reinterpret_cast<const float4*>(relTk + d0 * 8);
    const float4* rp1 = reinterpret_cast<const float4*>(relTk + (d0 - 64) * 8);
    float4 qa0 = qp0[0], qb0 = qp0[1], qa1 = qp1[0], qb1 = qp1[1];
    float4 ra0 = rp0[0], rb0 = rp0[1], ra1 = rp1[0], rb1 = rp1[1];
    float S0 = q0r[0]*ka.x + q0r[1]*ka.y + q0r[2]*ka.z + q0r[3]*ka.w
             + q0r[4]*kb.x + q0r[5]*kb.y + q0r[6]*kb.z + q0r[7]*kb.w;
    float S1 = q1r[0]*ka.x + q1r[1]*ka.y + q1r[2]*ka.z + q1r[3]*ka.w
             + q1r[4]*kb.x + q1r[5]*kb.y + q1r[6]*kb.z + q1r[7]*kb.w;
    float QR0 = q0r[0]*qa0.x + q0r[1]*qa0.y + q0r[2]*qa0.z + q0r[3]*qa0.w
              + q0r[4]*qb0.x + q0r[5]*qb0.y + q0r[6]*qb0.z + q0r[7]*qb0.w;
    float QR1 = q1r[0]*qa1.x + q1r[1]*qa1.y + q1r[2]*qa1.z + q1r[3]*qa1.w
              + q1r[4]*qb1.x + q1r[5]*qb1.y + q1r[6]*qb1.z + q1r[7]*qb1.w;
    float KR0 = ka.x*ra0.x + ka.y*ra0.y + ka.z*ra0.z + ka.w*ra0.w
              + kb.x*rb0.x + kb.y*rb0.y + kb.z*rb0.z + kb.w*rb0.w;
    float KR1 = ka.x*ra1.x + ka.y*ra1.y + ka.z*ra1.z + ka.w*ra1.w
              + kb.x*rb1.x + kb.y*rb1.y + kb.z*rb1.z + kb.w*rb1.w;
    float a0 = fmaf(S0, aS, fmaf(QR0, aQR, fmaf(KR0, aKR, offs)));
    float a1 = fmaf(S1, aS, fmaf(QR1, aQR, fmaf(KR1, aKR, offs)));
    float e0 = __expf(a0);
    float e1 = __expf(a1);
    l0 += e0; l1 += e1;
    float4 v0 = *reinterpret_cast<const float4*>(Vp + j * 16);
    float4 v1 = *reinterpret_cast<const float4*>(Vp + j * 16 + 4);
    float4 v2 = *reinterpret_cast<const float4*>(Vp + j * 16 + 8);
    float4 v3 = *reinterpret_cast<const float4*>(Vp + j * 16 + 12);
    asv0[0]  += e0*v0.x; asv0[1]  += e0*v0.y; asv0[2]  += e0*v0.z; asv0[3]  += e0*v0.w;
    asv0[4]  += e0*v1.x; asv0[5]  += e0*v1.y; asv0[6]  += e0*v1.z; asv0[7]  += e0*v1.w;
    asv0[8]  += e0*v2.x; asv0[9]  += e0*v2.y; asv0[10] += e0*v2.z; asv0[11] += e0*v2.w;
    asv0[12] += e0*v3.x; asv0[13] += e0*v3.y; asv0[14] += e0*v3.z; asv0[15] += e0*v3.w;
    asv1[0]  += e1*v0.x; asv1[1]  += e1*v0.y; asv1[2]  += e1*v0.z; asv1[3]  += e1*v0.w;
    asv1[4]  += e1*v1.x; asv1[5]  += e1*v1.y; asv1[6]  += e1*v1.z; asv1[7]  += e1*v1.w;
    asv1[8]  += e1*v2.x; asv1[9]  += e1*v2.y; asv1[10] += e1*v2.z; asv1[11] += e1*v2.w;
    asv1[12] += e1*v3.x; asv1[13] += e1*v3.y; asv1[14] += e1*v3.z; asv1[15] += e1*v3.w;
    // v_rel gathers: 16B rows, consecutive-d lanes -> conflict-free b128
    float4 wa0 = *reinterpret_cast<const float4*>(&Wh[0][d0][0]);
    float4 wb0 = *reinterpret_cast<const float4*>(&Wh[1][d0][0]);
    float4 wa1 = *reinterpret_cast<const float4*>(&Wh[0][d0 - 64][0]);
    float4 wb1 = *reinterpret_cast<const float4*>(&Wh[1][d0 - 64][0]);
    __half2 eh0 = __float2half2_rn(e0), eh1 = __float2half2_rn(e1);
    {
      const __half2* pa = reinterpret_cast<const __half2*>(&wa0);
      const __half2* pb = reinterpret_cast<const __half2*>(&wb0);
      ha0[0] = __hfma2(eh0, pa[0], ha0[0]); ha0[1] = __hfma2(eh0, pa[1], ha0[1]);
      ha0[2] = __hfma2(eh0, pa[2], ha0[2]); ha0[3] = __hfma2(eh0, pa[3], ha0[3]);
      ha0[4] = __hfma2(eh0, pb[0], ha0[4]); ha0[5] = __hfma2(eh0, pb[1], ha0[5]);
      ha0[6] = __hfma2(eh0, pb[2], ha0[6]); ha0[7] = __hfma2(eh0, pb[3], ha0[7]);
    }
    {
      const __half2* pa = reinterpret_cast<const __half2*>(&wa1);
      const __half2* pb = reinterpret_cast<const __half2*>(&wb1);
      ha1[0] = __hfma2(eh1, pa[0], ha1[0]); ha1[1] = __hfma2(eh1, pa[1], ha1[1]);
      ha1[2] = __hfma2(eh1, pa[2], ha1[2]); ha1[3] = __hfma2(eh1, pa[3], ha1[3]);
      ha1[4] = __hfma2(eh1, pb[0], ha1[4]); ha1[5] = __hfma2(eh1, pb[1], ha1[5]);
      ha1[6] = __hfma2(eh1, pb[2], ha1[6]); ha1[7] = __hfma2(eh1, pb[3], ha1[7]);
    }
  }
  float li0 = 1.f / l0, li1 = 1.f / l1;
  float* osv0  = svT  + (size_t)slice * 2048 + i0;
  float* osve0 = sveT + (size_t)slice * 2048 + i0;
  float* osv1  = svT  + (size_t)slice * 2048 + i1;
  float* osve1 = sveT + (size_t)slice * 2048 + i1;
#pragma unroll
  for (int c = 0; c < 16; ++c) {
    float h0 = (c & 1) ? __high2float(ha0[c >> 1]) : __low2float(ha0[c >> 1]);
    float h1 = (c & 1) ? __high2float(ha1[c >> 1]) : __low2float(ha1[c >> 1]);
    osv0[c * 128]  = asv0[c] * li0;
    osve0[c * 128] = h0 * li0;
    osv1[c * 128]  = asv1[c] * li1;
    osve1[c * 128] = h1 * li1;
  }
}

// ---------------- per-channel stats of sv/sve ----------------
__global__ __launch_bounds__(256) void k_sv_stats(const float* __restrict__ svT, const float* __restrict__ sveT,
                                                  double* __restrict__ statsSV) {
  __shared__ float r1[4], r2[4];
  int ch = blockIdx.x;  // 0-127 sv, 128-255 sve
  const float* base = (ch < 128) ? svT : sveT;
  int c = ch & 127, g = c >> 4, cc = c & 15;
  float s = 0.f, s2 = 0.f;
  for (int idx = threadIdx.x; idx < 32768; idx += 256) {
    int bw = idx >> 7, ii = idx & 127;
    int bb = bw >> 7, wwi = bw & 127;
    float v = base[(size_t)(((bb * 8 + g) * 128) + wwi) * 2048 + cc * 128 + ii];
    s += v; s2 += v * v;
  }
  s = warp_sum(s); s2 = warp_sum(s2);
  int wid = threadIdx.x >> 6;
  if ((threadIdx.x & 63) == 0) { r1[wid] = s; r2[wid] = s2; }
  __syncthreads();
  if (threadIdx.x == 0) {
    statsSV[2 * ch]     = (double)(r1[0] + r1[1] + r1[2] + r1[3]);
    statsSV[2 * ch + 1] = (double)(r2[0] + r2[1] + r2[2] + r2[3]);
  }
}

// ---------------- final: out = bn(sv)+bn(sve), transpose (w,i)->(i,w) ----------------
__global__ __launch_bounds__(256) void k_final(const float* __restrict__ svT, const float* __restrict__ sveT,
                                               const double* __restrict__ statsSV,
                                               const float* __restrict__ bnsv_g, const float* __restrict__ bnsv_b,
                                               const float* __restrict__ bnsve_g, const float* __restrict__ bnsve_b,
                                               float* __restrict__ out) {
  __shared__ float t[32][33];
  int plane = blockIdx.y;  // b*128 + c
  int b = plane >> 7, c = plane & 127;
  int g = c >> 4, cc = c & 15;
  double s = statsSV[2 * c], s2 = statsSV[2 * c + 1];
  double mu1 = s * (1.0 / 32768.0);
  float var1 = (float)(s2 * (1.0 / 32768.0) - mu1 * mu1);
  float sc1 = bnsv_g[c] * rsqrtf(var1 + 1e-5f);
  float sh1 = bnsv_b[c] - (float)mu1 * sc1;
  double se = statsSV[2 * (128 + c)], se2 = statsSV[2 * (128 + c) + 1];
  double mu2 = se * (1.0 / 32768.0);
  float var2 = (float)(se2 * (1.0 / 32768.0) - mu2 * mu2);
  float sc2 = bnsve_g[c] * rsqrtf(var2 + 1e-5f);
  float sh2 = bnsve_b[c] - (float)mu2 * sc2;
  int tw = (blockIdx.x & 3) * 32, ti = (blockIdx.x >> 2) * 32;
  int lx = threadIdx.x, ly = threadIdx.y;
#pragma unroll
  for (int r = ly; r < 32; r += 8) {
    int wr = tw + r, ii = ti + lx;
    size_t off = (size_t)((b * 8 + g) * 128 + wr) * 2048 + cc * 128 + ii;
    t[r][lx] = svT[off] * sc1 + sh1 + sveT[off] * sc2 + sh2;
  }
  __syncthreads();
#pragma unroll
  for (int r = ly; r < 32; r += 8)
    out[(size_t)plane * HW + (ti + r) * 128 + tw + lx] = t[lx][r];
}

extern "C" void kernel_launch(void* const* d_in, const int* in_sizes, int n_in,
                              void* d_out, int out_size, void* d_ws, size_t ws_size,
                              hipStream_t stream) {
  const float* x      = (const float*)d_in[0];
  const float* wq     = (const float*)d_in[1];
  const float* wk     = (const float*)d_in[2];
  const float* wv     = (const float*)d_in[3];
  const float* q_rel  = (const float*)d_in[4];
  const float* k_rel  = (const float*)d_in[5];
  const float* v_rel  = (const float*)d_in[6];
  const float* bnq_g  = (const float*)d_in[7];
  const float* bnq_b  = (const float*)d_in[8];
  const float* bnk_g  = (const float*)d_in[9];
  const float* bnk_b  = (const float*)d_in[10];
  const float* bnv_g  = (const float*)d_in[11];
  const float* bnv_b  = (const float*)d_in[12];
  const float* bnqk_g = (const float*)d_in[13];
  const float* bnqk_b = (const float*)d_in[14];
  const float* bnqr_g = (const float*)d_in[15];
  const float* bnqr_b = (const float*)d_in[16];
  const float* bnkr_g = (const float*)d_in[17];
  const float* bnkr_b = (const float*)d_in[18];
  const float* bnsv_g = (const float*)d_in[19];
  const float* bnsv_b = (const float*)d_in[20];
  const float* bnsve_g = (const float*)d_in[21];
  const float* bnsve_b = (const float*)d_in[22];
  float* out = (float*)d_out;

  float* wsf  = (float*)d_ws;
  float* xT   = wsf;              // 4,194,304 floats (reused as svT later: lifetimes disjoint)
  float* svT  = wsf;
  float* qkvT = wsf + 4194304;    // 8,388,608 floats
  float* sveT = wsf + 12582912;   // 4,194,304 floats
  float* tabs = wsf + 16777216;   // 11,264 floats; after k_qkr_stats reused as relT (4,080 floats)
  float* relTq = tabs;
  float* relTk = tabs + 2040;
  float* WT   = wsf + 16788480;   // 32,768 floats
  double* statsQKV = (double*)(wsf + 16821248);  // 512 doubles
  double* statsA   = statsQKV + 512;             // 48 doubles
  double* statsSV  = statsA + 48;                // 512 doubles

  hipMemsetAsync(statsA, 0, 48 * sizeof(double), stream);
  k_transpose<<<dim3(16, 256), dim3(32, 8), 0, stream>>>(x, xT);
  k_wT<<<128, 256, 0, stream>>>(wq, wk, wv, WT);
  k_qkv<<<dim3(256, 4, 2), 256, 0, stream>>>(xT, WT, qkvT);
  k_qkv_stats<<<256, 256, 0, stream>>>(qkvT, statsQKV);
  k_rel_tables<<<88, 128, 0, stream>>>(q_rel, k_rel, tabs);
  k_qkr_stats<<<2048, 128, 0, stream>>>(qkvT, statsQKV, bnq_g, bnq_b, bnk_g, bnk_b, tabs, statsA);
  k_relT<<<16, 256, 0, stream>>>(q_rel, k_rel, relTq);  // overwrites tabs (dead after k_qkr_stats)
  k_attn<<<512, 256, 0, stream>>>(qkvT, statsQKV, statsA, relTq, relTk, v_rel,
                                  bnq_g, bnq_b, bnk_g, bnk_b, bnv_g, bnv_b,
                                  bnqk_g, bnqk_b, bnqr_g, bnqr_b, bnkr_g, bnkr_b,
                                  svT, sveT);
  k_sv_stats<<<256, 256, 0, stream>>>(svT, sveT, statsSV);
  k_final<<<dim3(16, 256), dim3(32, 8), 0, stream>>>(svT, sveT, statsSV,
                                                     bnsv_g, bnsv_b, bnsve_g, bnsve_b, out);
  (void)in_sizes; (void)n_in; (void)out_size; (void)ws_size;
}